// Round 1
// baseline (2587.650 us; speedup 1.0000x reference)
//
#include <hip/hip_runtime.h>

#define NB 256
#define F 1024
#define S 128
#define H 16
#define D 64          // head dim for q/k and v (1024/16)
#define CHUNK 64      // i-chunk for phase-1 staging
#define WSTRIDE 68    // padded [i][d] stride (16B-aligned rows: 68*4=272)

union Smem {
    struct { float xs[CHUNK * S]; float wq[CHUNK * WSTRIDE]; float wk[CHUNK * WSTRIDE]; } p1; // 67.5 KB
    struct { float A[D * S]; float Bm[D * S]; } p2;                                           // 64 KB
    struct { float E[S * S]; float c[S]; float w[S]; } p3;                                    // 65 KB
};

__launch_bounds__(256, 2)
__global__ void attn_fused(const float* __restrict__ x,
                           const float* __restrict__ Wq,
                           const float* __restrict__ bq,
                           const float* __restrict__ Wk,
                           const float* __restrict__ bk,
                           const float* __restrict__ Wo,
                           const float* __restrict__ bo,
                           float* __restrict__ out)
{
    __shared__ Smem sm;
    const int tid = threadIdx.x;
    const int b = blockIdx.x >> 4;
    const int h = blockIdx.x & 15;

    // ---------------- Phase 1: Qh(64x128), Kh(64x128) = W_head @ x[b] ----------------
    // thread tile: 8 d-values x 4 s-values for each of A (Q) and B (K)
    const int st = tid & 31;        // s-tile 0..31
    const int dt = tid >> 5;        // d-tile 0..7
    const int s0 = st * 4;
    const int d0 = dt * 8;

    float accA[8][4];
    float accB[8][4];
#pragma unroll
    for (int r = 0; r < 8; ++r)
#pragma unroll
        for (int c = 0; c < 4; ++c) { accA[r][c] = 0.f; accB[r][c] = 0.f; }

    const float* xb  = x  + (size_t)b * F * S;
    const float* wqh = Wq + (size_t)(h * D) * F;
    const float* wkh = Wk + (size_t)(h * D) * F;

    for (int c0 = 0; c0 < F; c0 += CHUNK) {
        __syncthreads();
        // stage x chunk: rows c0..c0+63, all 128 s -> 8192 contiguous floats
        {
            const float4* xg  = (const float4*)(xb + (size_t)c0 * S);
            float4*       xs4 = (float4*)sm.p1.xs;
#pragma unroll
            for (int j = 0; j < 8; ++j) xs4[tid + j * 256] = xg[tid + j * 256];
        }
        // stage Wq/Wk tiles transposed to [i][d]
#pragma unroll
        for (int j = 0; j < 4; ++j) {
            const int fidx = tid + j * 256;      // 0..1023
            const int dd = fidx >> 4;            // 0..63
            const int ii = (fidx & 15) << 2;     // 0..60
            const float4 vq = *(const float4*)(wqh + (size_t)dd * F + c0 + ii);
            const float4 vk = *(const float4*)(wkh + (size_t)dd * F + c0 + ii);
            sm.p1.wq[(ii + 0) * WSTRIDE + dd] = vq.x;
            sm.p1.wq[(ii + 1) * WSTRIDE + dd] = vq.y;
            sm.p1.wq[(ii + 2) * WSTRIDE + dd] = vq.z;
            sm.p1.wq[(ii + 3) * WSTRIDE + dd] = vq.w;
            sm.p1.wk[(ii + 0) * WSTRIDE + dd] = vk.x;
            sm.p1.wk[(ii + 1) * WSTRIDE + dd] = vk.y;
            sm.p1.wk[(ii + 2) * WSTRIDE + dd] = vk.z;
            sm.p1.wk[(ii + 3) * WSTRIDE + dd] = vk.w;
        }
        __syncthreads();

#pragma unroll 4
        for (int i = 0; i < CHUNK; ++i) {
            const float4 xv = *(const float4*)&sm.p1.xs[i * S + s0];
            const float4 q0 = *(const float4*)&sm.p1.wq[i * WSTRIDE + d0];
            const float4 q1 = *(const float4*)&sm.p1.wq[i * WSTRIDE + d0 + 4];
            const float4 k0 = *(const float4*)&sm.p1.wk[i * WSTRIDE + d0];
            const float4 k1 = *(const float4*)&sm.p1.wk[i * WSTRIDE + d0 + 4];
            const float xa[4] = {xv.x, xv.y, xv.z, xv.w};
            const float qa[8] = {q0.x, q0.y, q0.z, q0.w, q1.x, q1.y, q1.z, q1.w};
            const float ka[8] = {k0.x, k0.y, k0.z, k0.w, k1.x, k1.y, k1.z, k1.w};
#pragma unroll
            for (int r = 0; r < 8; ++r)
#pragma unroll
                for (int c = 0; c < 4; ++c) {
                    accA[r][c] = fmaf(qa[r], xa[c], accA[r][c]);
                    accB[r][c] = fmaf(ka[r], xa[c], accB[r][c]);
                }
        }
    }

    // write Q/K heads (+bias) to LDS as [d][s]
    __syncthreads();
#pragma unroll
    for (int r = 0; r < 8; ++r) {
        const float bqv = bq[h * D + d0 + r];
        const float bkv = bk[h * D + d0 + r];
        *(float4*)&sm.p2.A [(d0 + r) * S + s0] =
            make_float4(accA[r][0] + bqv, accA[r][1] + bqv, accA[r][2] + bqv, accA[r][3] + bqv);
        *(float4*)&sm.p2.Bm[(d0 + r) * S + s0] =
            make_float4(accB[r][0] + bkv, accB[r][1] + bkv, accB[r][2] + bkv, accB[r][3] + bkv);
    }
    __syncthreads();

    // ---------------- Phase 2: scores[s][t] = sum_d A[d][s]*B[d][t] ----------------
    const int st2 = tid & 15;       // t-tile 0..15
    const int ss  = tid >> 4;       // s-tile 0..15
    const int ts0 = st2 * 8;
    const int rs0 = ss * 8;

    float sc[8][8];
#pragma unroll
    for (int r = 0; r < 8; ++r)
#pragma unroll
        for (int t = 0; t < 8; ++t) sc[r][t] = 0.f;

    for (int d = 0; d < D; ++d) {
        const float4 a0 = *(const float4*)&sm.p2.A [d * S + rs0];
        const float4 a1 = *(const float4*)&sm.p2.A [d * S + rs0 + 4];
        const float4 b0 = *(const float4*)&sm.p2.Bm[d * S + ts0];
        const float4 b1 = *(const float4*)&sm.p2.Bm[d * S + ts0 + 4];
        const float av[8] = {a0.x, a0.y, a0.z, a0.w, a1.x, a1.y, a1.z, a1.w};
        const float bv[8] = {b0.x, b0.y, b0.z, b0.w, b1.x, b1.y, b1.z, b1.w};
#pragma unroll
        for (int r = 0; r < 8; ++r)
#pragma unroll
            for (int t = 0; t < 8; ++t) sc[r][t] = fmaf(av[r], bv[t], sc[r][t]);
    }

    // ---------------- Phase 3: softmax over t (rows split across 16 lanes) ----------------
    float lsum[8];
#pragma unroll
    for (int r = 0; r < 8; ++r) {
        float m = sc[r][0];
#pragma unroll
        for (int t = 1; t < 8; ++t) m = fmaxf(m, sc[r][t]);
#pragma unroll
        for (int off = 1; off < 16; off <<= 1) m = fmaxf(m, __shfl_xor(m, off));
        float l = 0.f;
#pragma unroll
        for (int t = 0; t < 8; ++t) {
            const float e = __expf((sc[r][t] - m) * 0.125f);  // 1/TEMP = 1/8
            sc[r][t] = e;
            l += e;
        }
#pragma unroll
        for (int off = 1; off < 16; off <<= 1) l += __shfl_xor(l, off);
        lsum[r] = l;
    }

    __syncthreads();  // all phase-2 reads of A/Bm complete before overwriting with E
#pragma unroll
    for (int r = 0; r < 8; ++r) {
        *(float4*)&sm.p3.E[(rs0 + r) * S + ts0]     = make_float4(sc[r][0], sc[r][1], sc[r][2], sc[r][3]);
        *(float4*)&sm.p3.E[(rs0 + r) * S + ts0 + 4] = make_float4(sc[r][4], sc[r][5], sc[r][6], sc[r][7]);
    }
    if (st2 == 0) {
#pragma unroll
        for (int r = 0; r < 8; ++r) sm.p3.c[rs0 + r] = Wo[rs0 + r] / lsum[r];
    }
    __syncthreads();

    // ---------------- Phase 4: w[t] = sum_s (Wo[s]/l[s]) * E[s][t] ----------------
    if (tid < S) {
        float acc = 0.f;
        for (int s = 0; s < S; ++s) acc = fmaf(sm.p3.c[s], sm.p3.E[s * S + tid], acc);
        sm.p3.w[tid] = acc;
    }
    __syncthreads();

    // ---------------- Phase 5: out[b, h*64+d] = sum_t w[t]*x[b,h*64+d,t] + bo ----------------
    {
        const int d    = tid >> 2;
        const int part = tid & 3;
        const float* xv = x + ((size_t)b * F + (size_t)(h * D + d)) * S + part * 32;
        float acc = 0.f;
#pragma unroll 8
        for (int t = 0; t < 32; ++t) acc = fmaf(sm.p3.w[part * 32 + t], xv[t], acc);
        acc += __shfl_xor(acc, 1);
        acc += __shfl_xor(acc, 2);
        if (part == 0) out[(size_t)b * F + h * D + d] = acc + bo[0];
    }
}

extern "C" void kernel_launch(void* const* d_in, const int* in_sizes, int n_in,
                              void* d_out, int out_size, void* d_ws, size_t ws_size,
                              hipStream_t stream) {
    const float* x  = (const float*)d_in[0];
    const float* Wq = (const float*)d_in[1];
    const float* bq = (const float*)d_in[2];
    const float* Wk = (const float*)d_in[3];
    const float* bk = (const float*)d_in[4];
    const float* Wo = (const float*)d_in[5];
    const float* bo = (const float*)d_in[6];
    float* out = (float*)d_out;
    attn_fused<<<dim3(NB * H), dim3(256), 0, stream>>>(x, Wq, bq, Wk, bk, Wo, bo, out);
}

// Round 2
// 457.766 us; speedup vs baseline: 5.6528x; 5.6528x over previous
//
#include <hip/hip_runtime.h>

#define F 1024
#define S 128
#define H 16
#define D 64
#define CK 64        // K-chunk per staging iteration
#define NCHUNK 16    // 1024 / 64

typedef short bf16x8 __attribute__((ext_vector_type(8)));
typedef float f32x4  __attribute__((ext_vector_type(4)));

// LDS: 2048 16B units (32 KB) + reduction scratch.
//   units [0,1024):    Ws (phase1: [Wq;Wk] rows 0..127, bf16)  -> aliased as Qs (rows=s, k=d)
//   units [1024,2048): Xs (phase1: x^T rows=s, k=i, bf16)      -> aliased as Ks (rows=t, k=d)
// unit(row, kc) = base + row*8 + (kc ^ (row & 7))   [XOR swizzle, conflict-free b128]
struct SmemT {
    uint4 mat[2048];
    float wpart[4][S];
    float wfin[S];
};

__device__ __forceinline__ unsigned short f2bf(float f) {
    unsigned u = __float_as_uint(f);
    u += 0x7fffu + ((u >> 16) & 1u);   // round-to-nearest-even
    return (unsigned short)(u >> 16);
}

__device__ __forceinline__ uint4 pack8(const float* f) {
    uint4 u;
    u.x = (unsigned)f2bf(f[0]) | ((unsigned)f2bf(f[1]) << 16);
    u.y = (unsigned)f2bf(f[2]) | ((unsigned)f2bf(f[3]) << 16);
    u.z = (unsigned)f2bf(f[4]) | ((unsigned)f2bf(f[5]) << 16);
    u.w = (unsigned)f2bf(f[6]) | ((unsigned)f2bf(f[7]) << 16);
    return u;
}

__launch_bounds__(256, 4)
__global__ void attn_fused(const float* __restrict__ x,
                           const float* __restrict__ Wq,
                           const float* __restrict__ bq,
                           const float* __restrict__ Wk,
                           const float* __restrict__ bk,
                           const float* __restrict__ Wo,
                           const float* __restrict__ bo,
                           float* __restrict__ out)
{
    __shared__ SmemT sm;
    const int tid  = threadIdx.x;
    const int lane = tid & 63;
    const int wv   = tid >> 6;
    const int l15  = lane & 15;
    const int q    = lane >> 4;

    // XCD-aware swizzle: per XCD, 4-head x 8-batch tiles for L2 locality
    const int g    = blockIdx.x;
    const int xcd  = g & 7;
    const int slot = g >> 3;            // 0..511
    const int hg   = slot >> 7;         // 0..3
    const int r0   = slot & 127;
    const int b    = xcd * 32 + (r0 >> 2);
    const int h    = hg * 4 + (r0 & 3);

    const float* xb  = x  + (size_t)b * (F * S);
    const float* wqh = Wq + (size_t)h * D * F;
    const float* wkh = Wk + (size_t)h * D * F;

    // ---------------- Phase 1: [Q;K] (128x128) = [Wq_h;Wk_h] (128x1024) @ x_b ----------------
    // wave tile: 64x64 (4x4 MFMA 16x16x32 tiles)
    const int m0 = (wv & 1) * 64;
    const int n0 = (wv >> 1) * 64;

    f32x4 acc[4][4];
#pragma unroll
    for (int mt = 0; mt < 4; ++mt)
#pragma unroll
        for (int nt = 0; nt < 4; ++nt) acc[mt][nt] = (f32x4){0.f, 0.f, 0.f, 0.f};

    const int mq  = tid >> 2;           // W staging: row pair (mq, 64+mq)
    const int kq  = tid & 3;            //   k range kq*16
    const int s0x = (tid & 63) * 2;     // X staging: s columns s0x, s0x+1
    const int iq  = tid >> 6;           //   i range iq*16

    for (int ch = 0; ch < NCHUNK; ++ch) {
        const int c0 = ch * CK;
        __syncthreads();
        // --- stage W (rows k-contiguous already; coalesced-ish, L2-hot) ---
        {
            const int key = mq & 7;
            float f[16];
            const float4* srcq = (const float4*)(wqh + (size_t)mq * F + (c0 + kq * 16));
#pragma unroll
            for (int j = 0; j < 4; ++j) {
                float4 v = srcq[j];
                f[4*j] = v.x; f[4*j+1] = v.y; f[4*j+2] = v.z; f[4*j+3] = v.w;
            }
            sm.mat[mq * 8 + ((kq * 2    ) ^ key)] = pack8(f);
            sm.mat[mq * 8 + ((kq * 2 + 1) ^ key)] = pack8(f + 8);
            const float4* srck = (const float4*)(wkh + (size_t)mq * F + (c0 + kq * 16));
#pragma unroll
            for (int j = 0; j < 4; ++j) {
                float4 v = srck[j];
                f[4*j] = v.x; f[4*j+1] = v.y; f[4*j+2] = v.z; f[4*j+3] = v.w;
            }
            sm.mat[(64 + mq) * 8 + ((kq * 2    ) ^ key)] = pack8(f);
            sm.mat[(64 + mq) * 8 + ((kq * 2 + 1) ^ key)] = pack8(f + 8);
        }
        // --- stage x^T (transpose via float2 column loads, coalesced across lanes) ---
        {
            const float* src = xb + (size_t)(c0 + iq * 16) * S + s0x;
            float fa[8], fb[8];
#pragma unroll
            for (int grp = 0; grp < 2; ++grp) {
#pragma unroll
                for (int j = 0; j < 8; ++j) {
                    float2 v = *(const float2*)(src + (size_t)(grp * 8 + j) * S);
                    fa[j] = v.x; fb[j] = v.y;
                }
                const int kc = iq * 2 + grp;
                sm.mat[1024 + (s0x    ) * 8 + (kc ^ ((s0x    ) & 7))] = pack8(fa);
                sm.mat[1024 + (s0x + 1) * 8 + (kc ^ ((s0x + 1) & 7))] = pack8(fb);
            }
        }
        __syncthreads();
        // --- MFMA: 2 k-steps of 32 over this chunk ---
#pragma unroll
        for (int ks = 0; ks < 2; ++ks) {
            bf16x8 af[4], br[4];
#pragma unroll
            for (int mt = 0; mt < 4; ++mt) {
                const int row = m0 + mt * 16 + l15;
                af[mt] = *(const bf16x8*)&sm.mat[row * 8 + ((ks * 4 + q) ^ (row & 7))];
            }
#pragma unroll
            for (int nt = 0; nt < 4; ++nt) {
                const int row = n0 + nt * 16 + l15;
                br[nt] = *(const bf16x8*)&sm.mat[1024 + row * 8 + ((ks * 4 + q) ^ (row & 7))];
            }
#pragma unroll
            for (int mt = 0; mt < 4; ++mt)
#pragma unroll
                for (int nt = 0; nt < 4; ++nt)
                    acc[mt][nt] = __builtin_amdgcn_mfma_f32_16x16x32_bf16(
                        af[mt], br[nt], acc[mt][nt], 0, 0, 0);
        }
    }

    // ---------------- Epilogue: +bias, cvt bf16, write Qs (rows=s,k=d) / Ks (rows=t,k=d) ----------------
    __syncthreads();   // all MFMA reads of Ws/Xs done before aliasing overwrite
    {
        unsigned short* m16 = (unsigned short*)sm.mat;
#pragma unroll
        for (int mt = 0; mt < 4; ++mt) {
#pragma unroll
            for (int rr = 0; rr < 4; ++rr) {
                const int m = m0 + mt * 16 + q * 4 + rr;          // C/D row = (lane>>4)*4 + reg
                const int d = m & 63;
                const float bias = (m < 64) ? bq[h * D + d] : bk[h * D + d];
                const int base = (m < 64) ? 0 : 8192;             // Qs units [0,1024), Ks [1024,2048)
#pragma unroll
                for (int nt = 0; nt < 4; ++nt) {
                    const int s = n0 + nt * 16 + l15;             // C/D col = lane&15
                    const float v = acc[mt][nt][rr] + bias;
                    const int unit = s * 8 + (((d >> 3)) ^ (s & 7));
                    m16[base + unit * 8 + (d & 7)] = f2bf(v);
                }
            }
        }
    }
    __syncthreads();

    // ---------------- Phase 2: scores (128x128) = Q^T @ K via MFMA; wave rows [wv*32, +32) ----------------
    f32x4 p[2][8];
#pragma unroll
    for (int mt = 0; mt < 2; ++mt)
#pragma unroll
        for (int nt = 0; nt < 8; ++nt) p[mt][nt] = (f32x4){0.f, 0.f, 0.f, 0.f};

#pragma unroll
    for (int ks = 0; ks < 2; ++ks) {
        bf16x8 a2[2], b2[8];
#pragma unroll
        for (int mt = 0; mt < 2; ++mt) {
            const int row = wv * 32 + mt * 16 + l15;
            a2[mt] = *(const bf16x8*)&sm.mat[row * 8 + ((ks * 4 + q) ^ (row & 7))];
        }
#pragma unroll
        for (int nt = 0; nt < 8; ++nt) {
            const int row = nt * 16 + l15;
            b2[nt] = *(const bf16x8*)&sm.mat[1024 + row * 8 + ((ks * 4 + q) ^ (row & 7))];
        }
#pragma unroll
        for (int mt = 0; mt < 2; ++mt)
#pragma unroll
            for (int nt = 0; nt < 8; ++nt)
                p[mt][nt] = __builtin_amdgcn_mfma_f32_16x16x32_bf16(a2[mt], b2[nt], p[mt][nt], 0, 0, 0);
    }

    // ---------------- Phase 3+4: softmax rows + fold Wo -> partial w[t] ----------------
    float pw[8];
#pragma unroll
    for (int nt = 0; nt < 8; ++nt) pw[nt] = 0.f;

#pragma unroll
    for (int mt = 0; mt < 2; ++mt) {
#pragma unroll
        for (int rr = 0; rr < 4; ++rr) {
            const int srow = wv * 32 + mt * 16 + q * 4 + rr;
            float mx = p[mt][0][rr];
#pragma unroll
            for (int nt = 1; nt < 8; ++nt) mx = fmaxf(mx, p[mt][nt][rr]);
#pragma unroll
            for (int off = 1; off < 16; off <<= 1) mx = fmaxf(mx, __shfl_xor(mx, off));
            float e[8];
            float l = 0.f;
#pragma unroll
            for (int nt = 0; nt < 8; ++nt) {
                e[nt] = __expf((p[mt][nt][rr] - mx) * 0.125f);   // 1/TEMP = 1/8
                l += e[nt];
            }
#pragma unroll
            for (int off = 1; off < 16; off <<= 1) l += __shfl_xor(l, off);
            const float c = Wo[srow] / l;
#pragma unroll
            for (int nt = 0; nt < 8; ++nt) pw[nt] = fmaf(c, e[nt], pw[nt]);
        }
    }
    // reduce across the 4 q-quads (same t = nt*16 + l15)
#pragma unroll
    for (int nt = 0; nt < 8; ++nt) {
        pw[nt] += __shfl_xor(pw[nt], 16);
        pw[nt] += __shfl_xor(pw[nt], 32);
    }
    if (q == 0) {
#pragma unroll
        for (int nt = 0; nt < 8; ++nt) sm.wpart[wv][nt * 16 + l15] = pw[nt];
    }
    __syncthreads();
    if (tid < S)
        sm.wfin[tid] = sm.wpart[0][tid] + sm.wpart[1][tid] + sm.wpart[2][tid] + sm.wpart[3][tid];
    __syncthreads();

    // ---------------- Phase 5: out[b, h*64+d] = sum_t w[t] * x[b, h*64+d, t] + bo ----------------
    {
        const int dd   = tid >> 2;
        const int part = tid & 3;
        const float* xv = xb + (size_t)(h * D + dd) * S + part * 32;
        float a5 = 0.f;
#pragma unroll 8
        for (int t = 0; t < 32; ++t) a5 = fmaf(sm.wfin[part * 32 + t], xv[t], a5);
        a5 += __shfl_xor(a5, 1);
        a5 += __shfl_xor(a5, 2);
        if (part == 0) out[(size_t)b * F + h * D + dd] = a5 + bo[0];
    }
}

extern "C" void kernel_launch(void* const* d_in, const int* in_sizes, int n_in,
                              void* d_out, int out_size, void* d_ws, size_t ws_size,
                              hipStream_t stream) {
    const float* x  = (const float*)d_in[0];
    const float* Wq = (const float*)d_in[1];
    const float* bq = (const float*)d_in[2];
    const float* Wk = (const float*)d_in[3];
    const float* bk = (const float*)d_in[4];
    const float* Wo = (const float*)d_in[5];
    const float* bo = (const float*)d_in[6];
    float* out = (float*)d_out;
    attn_fused<<<dim3(256 * H), dim3(256), 0, stream>>>(x, Wq, bq, Wk, bk, Wo, bo, out);
}

// Round 3
// 367.484 us; speedup vs baseline: 7.0415x; 1.2457x over previous
//
#include <hip/hip_runtime.h>

#define F 1024
#define S 128
#define H 16
#define D 64
#define CK 64        // K-chunk per staging iteration
#define NCHUNK 16    // 1024 / 64

typedef short bf16x8 __attribute__((ext_vector_type(8)));
typedef float f32x4  __attribute__((ext_vector_type(4)));

// ws layout: xs[256 b][16 ch][1024 units] bf16-swizzled x, then wb[16 h][16 ch][1024 units]
#define XS_UNITS ((size_t)256 * NCHUNK * 1024)
#define WB_UNITS ((size_t)16 * NCHUNK * 1024)
#define WS_NEED ((XS_UNITS + WB_UNITS) * 16)

// LDS: 2048 16B units (32 KB) + reduction scratch.
//   units [0,1024):    Ws (phase1: [Wq;Wk] rows 0..127, bf16)  -> aliased as Qs (rows=s, k=d)
//   units [1024,2048): Xs (phase1: x^T rows=s, k=i, bf16)      -> aliased as Ks (rows=t, k=d)
// unit(row, kc) = base + row*8 + (kc ^ (row & 7))   [XOR swizzle, conflict-free b128]
struct SmemT {
    uint4 mat[2048];
    float wpart[4][S];
    float wfin[S];
};

__device__ __forceinline__ unsigned short f2bf(float f) {
    unsigned u = __float_as_uint(f);
    u += 0x7fffu + ((u >> 16) & 1u);   // round-to-nearest-even
    return (unsigned short)(u >> 16);
}

__device__ __forceinline__ uint4 pack8(const float* f) {
    uint4 u;
    u.x = (unsigned)f2bf(f[0]) | ((unsigned)f2bf(f[1]) << 16);
    u.y = (unsigned)f2bf(f[2]) | ((unsigned)f2bf(f[3]) << 16);
    u.z = (unsigned)f2bf(f[4]) | ((unsigned)f2bf(f[5]) << 16);
    u.w = (unsigned)f2bf(f[6]) | ((unsigned)f2bf(f[7]) << 16);
    return u;
}

typedef __attribute__((address_space(1))) const unsigned int as1_u32;
typedef __attribute__((address_space(3))) unsigned int as3_u32;

__device__ __forceinline__ void async_cp16(const uint4* g, uint4* l) {
    __builtin_amdgcn_global_load_lds((as1_u32*)g, (as3_u32*)l, 16, 0, 0);
}

// ---------------- prep: fp32 -> bf16, transpose + XOR-swizzle into LDS-unit order ----------------
__global__ void prep(const float* __restrict__ x,
                     const float* __restrict__ Wq,
                     const float* __restrict__ Wk,
                     uint4* __restrict__ xs,
                     uint4* __restrict__ wb)
{
    __shared__ float tile[64 * 129];
    const int tid = threadIdx.x;
    const int blk = blockIdx.x;
    if (blk < 4096) {
        // x tile: b, chunk ch -> 64 i-rows x 128 s, transposed to units [s][kc]
        const int b = blk >> 4, ch = blk & 15;
        const float4* src = (const float4*)(x + ((size_t)b * F + ch * CK) * S);
        float4 v[8];
#pragma unroll
        for (int j = 0; j < 8; ++j) v[j] = src[tid + j * 256];
#pragma unroll
        for (int j = 0; j < 8; ++j) {
            const int e4 = tid + j * 256;
            const int i  = e4 >> 5;
            const int sc = (e4 & 31) * 4;
            tile[i * 129 + sc + 0] = v[j].x;
            tile[i * 129 + sc + 1] = v[j].y;
            tile[i * 129 + sc + 2] = v[j].z;
            tile[i * 129 + sc + 3] = v[j].w;
        }
        __syncthreads();
#pragma unroll
        for (int j = 0; j < 4; ++j) {
            const int u   = tid + j * 256;
            const int s   = u >> 3;
            const int kc  = (u & 7) ^ (s & 7);
            float f[8];
#pragma unroll
            for (int jj = 0; jj < 8; ++jj) f[jj] = tile[(kc * 8 + jj) * 129 + s];
            xs[((size_t)(b * NCHUNK + ch)) * 1024 + u] = pack8(f);
        }
    } else {
        // W tile: h, chunk ch -> rows 0..127 = [Wq_h; Wk_h], k-contiguous, swizzled
        const int blk2 = blk - 4096;
        const int h = blk2 >> 4, ch = blk2 & 15;
#pragma unroll
        for (int j = 0; j < 4; ++j) {
            const int u   = tid + j * 256;
            const int row = u >> 3;
            const int kc  = (u & 7) ^ (row & 7);
            const float* src = (row < 64)
                ? (Wq + (size_t)(h * D + row) * F + ch * CK + kc * 8)
                : (Wk + (size_t)(h * D + row - 64) * F + ch * CK + kc * 8);
            float f[8];
            float4 a = ((const float4*)src)[0];
            float4 c = ((const float4*)src)[1];
            f[0] = a.x; f[1] = a.y; f[2] = a.z; f[3] = a.w;
            f[4] = c.x; f[5] = c.y; f[6] = c.z; f[7] = c.w;
            wb[((size_t)(h * NCHUNK + ch)) * 1024 + u] = pack8(f);
        }
    }
}

// ---------------- main: DMA staging + MFMA + softmax + folded epilogue ----------------
__launch_bounds__(256, 4)
__global__ void attn_main(const float* __restrict__ x,
                          const uint4* __restrict__ xs,
                          const uint4* __restrict__ wb,
                          const float* __restrict__ bq,
                          const float* __restrict__ bk,
                          const float* __restrict__ Wo,
                          const float* __restrict__ bo,
                          float* __restrict__ out)
{
    __shared__ SmemT sm;
    const int tid  = threadIdx.x;
    const int lane = tid & 63;
    const int wv   = tid >> 6;
    const int l15  = lane & 15;
    const int q    = lane >> 4;

    // XCD-aware swizzle: per XCD, 4-head x 8-batch tiles for L2 locality
    const int g    = blockIdx.x;
    const int xcd  = g & 7;
    const int slot = g >> 3;
    const int hg   = slot >> 7;
    const int r0   = slot & 127;
    const int b    = xcd * 32 + (r0 >> 2);
    const int h    = hg * 4 + (r0 & 3);

    const float* xb = x + (size_t)b * (F * S);
    const uint4* xc = xs + ((size_t)b * NCHUNK) * 1024;
    const uint4* wc = wb + ((size_t)h * NCHUNK) * 1024;

    // ---------------- Phase 1: [Q;K] (128x128) = [Wq_h;Wk_h] (128x1024) @ x_b ----------------
    const int m0 = (wv & 1) * 64;
    const int n0 = (wv >> 1) * 64;

    f32x4 acc[4][4];
#pragma unroll
    for (int mt = 0; mt < 4; ++mt)
#pragma unroll
        for (int nt = 0; nt < 4; ++nt) acc[mt][nt] = (f32x4){0.f, 0.f, 0.f, 0.f};

    for (int ch = 0; ch < NCHUNK; ++ch) {
        __syncthreads();
        // --- pure-DMA staging: 32 KB linear copy (pre-swizzled by prep) ---
        const uint4* wg = wc + ch * 1024 + wv * 256;
        const uint4* xg = xc + ch * 1024 + wv * 256;
#pragma unroll
        for (int k = 0; k < 4; ++k)
            async_cp16(wg + k * 64 + lane, &sm.mat[wv * 256 + k * 64]);
#pragma unroll
        for (int k = 0; k < 4; ++k)
            async_cp16(xg + k * 64 + lane, &sm.mat[1024 + wv * 256 + k * 64]);
        __syncthreads();
        // --- MFMA: 2 k-steps of 32 over this chunk ---
#pragma unroll
        for (int ks = 0; ks < 2; ++ks) {
            bf16x8 af[4], br[4];
#pragma unroll
            for (int mt = 0; mt < 4; ++mt) {
                const int row = m0 + mt * 16 + l15;
                af[mt] = *(const bf16x8*)&sm.mat[row * 8 + ((ks * 4 + q) ^ (row & 7))];
            }
#pragma unroll
            for (int nt = 0; nt < 4; ++nt) {
                const int row = n0 + nt * 16 + l15;
                br[nt] = *(const bf16x8*)&sm.mat[1024 + row * 8 + ((ks * 4 + q) ^ (row & 7))];
            }
#pragma unroll
            for (int mt = 0; mt < 4; ++mt)
#pragma unroll
                for (int nt = 0; nt < 4; ++nt)
                    acc[mt][nt] = __builtin_amdgcn_mfma_f32_16x16x32_bf16(
                        af[mt], br[nt], acc[mt][nt], 0, 0, 0);
        }
    }

    // ---------------- Epilogue: +bias, cvt bf16, write Qs (rows=s,k=d) / Ks (rows=t,k=d) ----------------
    __syncthreads();
    {
        unsigned short* m16 = (unsigned short*)sm.mat;
#pragma unroll
        for (int mt = 0; mt < 4; ++mt) {
#pragma unroll
            for (int rr = 0; rr < 4; ++rr) {
                const int m = m0 + mt * 16 + q * 4 + rr;          // C/D row = (lane>>4)*4 + reg
                const int d = m & 63;
                const float bias = (m < 64) ? bq[h * D + d] : bk[h * D + d];
                const int base = (m < 64) ? 0 : 8192;
#pragma unroll
                for (int nt = 0; nt < 4; ++nt) {
                    const int s = n0 + nt * 16 + l15;             // C/D col = lane&15
                    const float v = acc[mt][nt][rr] + bias;
                    const int unit = s * 8 + (((d >> 3)) ^ (s & 7));
                    m16[base + unit * 8 + (d & 7)] = f2bf(v);
                }
            }
        }
    }
    __syncthreads();

    // ---------------- Phase 2: scores (128x128) = Q^T @ K via MFMA; wave rows [wv*32, +32) ----------------
    f32x4 p[2][8];
#pragma unroll
    for (int mt = 0; mt < 2; ++mt)
#pragma unroll
        for (int nt = 0; nt < 8; ++nt) p[mt][nt] = (f32x4){0.f, 0.f, 0.f, 0.f};

#pragma unroll
    for (int ks = 0; ks < 2; ++ks) {
        bf16x8 a2[2], b2[8];
#pragma unroll
        for (int mt = 0; mt < 2; ++mt) {
            const int row = wv * 32 + mt * 16 + l15;
            a2[mt] = *(const bf16x8*)&sm.mat[row * 8 + ((ks * 4 + q) ^ (row & 7))];
        }
#pragma unroll
        for (int nt = 0; nt < 8; ++nt) {
            const int row = nt * 16 + l15;
            b2[nt] = *(const bf16x8*)&sm.mat[1024 + row * 8 + ((ks * 4 + q) ^ (row & 7))];
        }
#pragma unroll
        for (int mt = 0; mt < 2; ++mt)
#pragma unroll
            for (int nt = 0; nt < 8; ++nt)
                p[mt][nt] = __builtin_amdgcn_mfma_f32_16x16x32_bf16(a2[mt], b2[nt], p[mt][nt], 0, 0, 0);
    }

    // ---------------- Phase 3+4: softmax rows + fold Wo -> partial w[t] ----------------
    float pw[8];
#pragma unroll
    for (int nt = 0; nt < 8; ++nt) pw[nt] = 0.f;

#pragma unroll
    for (int mt = 0; mt < 2; ++mt) {
#pragma unroll
        for (int rr = 0; rr < 4; ++rr) {
            const int srow = wv * 32 + mt * 16 + q * 4 + rr;
            float mx = p[mt][0][rr];
#pragma unroll
            for (int nt = 1; nt < 8; ++nt) mx = fmaxf(mx, p[mt][nt][rr]);
#pragma unroll
            for (int off = 1; off < 16; off <<= 1) mx = fmaxf(mx, __shfl_xor(mx, off));
            float e[8];
            float l = 0.f;
#pragma unroll
            for (int nt = 0; nt < 8; ++nt) {
                e[nt] = __expf((p[mt][nt][rr] - mx) * 0.125f);   // 1/TEMP = 1/8
                l += e[nt];
            }
#pragma unroll
            for (int off = 1; off < 16; off <<= 1) l += __shfl_xor(l, off);
            const float c = Wo[srow] / l;
#pragma unroll
            for (int nt = 0; nt < 8; ++nt) pw[nt] = fmaf(c, e[nt], pw[nt]);
        }
    }
#pragma unroll
    for (int nt = 0; nt < 8; ++nt) {
        pw[nt] += __shfl_xor(pw[nt], 16);
        pw[nt] += __shfl_xor(pw[nt], 32);
    }
    if (q == 0) {
#pragma unroll
        for (int nt = 0; nt < 8; ++nt) sm.wpart[wv][nt * 16 + l15] = pw[nt];
    }
    __syncthreads();
    if (tid < S)
        sm.wfin[tid] = sm.wpart[0][tid] + sm.wpart[1][tid] + sm.wpart[2][tid] + sm.wpart[3][tid];
    __syncthreads();

    // ---------------- Phase 5: out[b, h*64+d] = sum_t w[t] * x[b, h*64+d, t] + bo ----------------
    {
        const int dd   = tid >> 2;
        const int part = tid & 3;
        const float* xv = xb + (size_t)(h * D + dd) * S + part * 32;
        float a5 = 0.f;
#pragma unroll 8
        for (int t = 0; t < 32; ++t) a5 = fmaf(sm.wfin[part * 32 + t], xv[t], a5);
        a5 += __shfl_xor(a5, 1);
        a5 += __shfl_xor(a5, 2);
        if (part == 0) out[(size_t)b * F + h * D + dd] = a5 + bo[0];
    }
}

// ---------------- fallback (round-2 self-contained kernel) if ws too small ----------------
__launch_bounds__(256, 4)
__global__ void attn_fallback(const float* __restrict__ x,
                              const float* __restrict__ Wq,
                              const float* __restrict__ bq,
                              const float* __restrict__ Wk,
                              const float* __restrict__ bk,
                              const float* __restrict__ Wo,
                              const float* __restrict__ bo,
                              float* __restrict__ out)
{
    __shared__ SmemT sm;
    const int tid  = threadIdx.x;
    const int lane = tid & 63;
    const int wv   = tid >> 6;
    const int l15  = lane & 15;
    const int q    = lane >> 4;

    const int g    = blockIdx.x;
    const int xcd  = g & 7;
    const int slot = g >> 3;
    const int hg   = slot >> 7;
    const int r0   = slot & 127;
    const int b    = xcd * 32 + (r0 >> 2);
    const int h    = hg * 4 + (r0 & 3);

    const float* xb  = x  + (size_t)b * (F * S);
    const float* wqh = Wq + (size_t)h * D * F;
    const float* wkh = Wk + (size_t)h * D * F;

    const int m0 = (wv & 1) * 64;
    const int n0 = (wv >> 1) * 64;

    f32x4 acc[4][4];
#pragma unroll
    for (int mt = 0; mt < 4; ++mt)
#pragma unroll
        for (int nt = 0; nt < 4; ++nt) acc[mt][nt] = (f32x4){0.f, 0.f, 0.f, 0.f};

    const int mq  = tid >> 2;
    const int kq  = tid & 3;
    const int s0x = (tid & 63) * 2;
    const int iq  = tid >> 6;

    for (int ch = 0; ch < NCHUNK; ++ch) {
        const int c0 = ch * CK;
        __syncthreads();
        {
            const int key = mq & 7;
            float f[16];
            const float4* srcq = (const float4*)(wqh + (size_t)mq * F + (c0 + kq * 16));
#pragma unroll
            for (int j = 0; j < 4; ++j) {
                float4 v = srcq[j];
                f[4*j] = v.x; f[4*j+1] = v.y; f[4*j+2] = v.z; f[4*j+3] = v.w;
            }
            sm.mat[mq * 8 + ((kq * 2    ) ^ key)] = pack8(f);
            sm.mat[mq * 8 + ((kq * 2 + 1) ^ key)] = pack8(f + 8);
            const float4* srck = (const float4*)(wkh + (size_t)mq * F + (c0 + kq * 16));
#pragma unroll
            for (int j = 0; j < 4; ++j) {
                float4 v = srck[j];
                f[4*j] = v.x; f[4*j+1] = v.y; f[4*j+2] = v.z; f[4*j+3] = v.w;
            }
            sm.mat[(64 + mq) * 8 + ((kq * 2    ) ^ key)] = pack8(f);
            sm.mat[(64 + mq) * 8 + ((kq * 2 + 1) ^ key)] = pack8(f + 8);
        }
        {
            const float* src = xb + (size_t)(c0 + iq * 16) * S + s0x;
            float fa[8], fb[8];
#pragma unroll
            for (int grp = 0; grp < 2; ++grp) {
#pragma unroll
                for (int j = 0; j < 8; ++j) {
                    float2 v = *(const float2*)(src + (size_t)(grp * 8 + j) * S);
                    fa[j] = v.x; fb[j] = v.y;
                }
                const int kc = iq * 2 + grp;
                sm.mat[1024 + (s0x    ) * 8 + (kc ^ ((s0x    ) & 7))] = pack8(fa);
                sm.mat[1024 + (s0x + 1) * 8 + (kc ^ ((s0x + 1) & 7))] = pack8(fb);
            }
        }
        __syncthreads();
#pragma unroll
        for (int ks = 0; ks < 2; ++ks) {
            bf16x8 af[4], br[4];
#pragma unroll
            for (int mt = 0; mt < 4; ++mt) {
                const int row = m0 + mt * 16 + l15;
                af[mt] = *(const bf16x8*)&sm.mat[row * 8 + ((ks * 4 + q) ^ (row & 7))];
            }
#pragma unroll
            for (int nt = 0; nt < 4; ++nt) {
                const int row = n0 + nt * 16 + l15;
                br[nt] = *(const bf16x8*)&sm.mat[1024 + row * 8 + ((ks * 4 + q) ^ (row & 7))];
            }
#pragma unroll
            for (int mt = 0; mt < 4; ++mt)
#pragma unroll
                for (int nt = 0; nt < 4; ++nt)
                    acc[mt][nt] = __builtin_amdgcn_mfma_f32_16x16x32_bf16(
                        af[mt], br[nt], acc[mt][nt], 0, 0, 0);
        }
    }

    __syncthreads();
    {
        unsigned short* m16 = (unsigned short*)sm.mat;
#pragma unroll
        for (int mt = 0; mt < 4; ++mt) {
#pragma unroll
            for (int rr = 0; rr < 4; ++rr) {
                const int m = m0 + mt * 16 + q * 4 + rr;
                const int d = m & 63;
                const float bias = (m < 64) ? bq[h * D + d] : bk[h * D + d];
                const int base = (m < 64) ? 0 : 8192;
#pragma unroll
                for (int nt = 0; nt < 4; ++nt) {
                    const int s = n0 + nt * 16 + l15;
                    const float v = acc[mt][nt][rr] + bias;
                    const int unit = s * 8 + (((d >> 3)) ^ (s & 7));
                    m16[base + unit * 8 + (d & 7)] = f2bf(v);
                }
            }
        }
    }
    __syncthreads();

    f32x4 p[2][8];
#pragma unroll
    for (int mt = 0; mt < 2; ++mt)
#pragma unroll
        for (int nt = 0; nt < 8; ++nt) p[mt][nt] = (f32x4){0.f, 0.f, 0.f, 0.f};

#pragma unroll
    for (int ks = 0; ks < 2; ++ks) {
        bf16x8 a2[2], b2[8];
#pragma unroll
        for (int mt = 0; mt < 2; ++mt) {
            const int row = wv * 32 + mt * 16 + l15;
            a2[mt] = *(const bf16x8*)&sm.mat[row * 8 + ((ks * 4 + q) ^ (row & 7))];
        }
#pragma unroll
        for (int nt = 0; nt < 8; ++nt) {
            const int row = nt * 16 + l15;
            b2[nt] = *(const bf16x8*)&sm.mat[1024 + row * 8 + ((ks * 4 + q) ^ (row & 7))];
        }
#pragma unroll
        for (int mt = 0; mt < 2; ++mt)
#pragma unroll
            for (int nt = 0; nt < 8; ++nt)
                p[mt][nt] = __builtin_amdgcn_mfma_f32_16x16x32_bf16(a2[mt], b2[nt], p[mt][nt], 0, 0, 0);
    }

    float pw[8];
#pragma unroll
    for (int nt = 0; nt < 8; ++nt) pw[nt] = 0.f;

#pragma unroll
    for (int mt = 0; mt < 2; ++mt) {
#pragma unroll
        for (int rr = 0; rr < 4; ++rr) {
            const int srow = wv * 32 + mt * 16 + q * 4 + rr;
            float mx = p[mt][0][rr];
#pragma unroll
            for (int nt = 1; nt < 8; ++nt) mx = fmaxf(mx, p[mt][nt][rr]);
#pragma unroll
            for (int off = 1; off < 16; off <<= 1) mx = fmaxf(mx, __shfl_xor(mx, off));
            float e[8];
            float l = 0.f;
#pragma unroll
            for (int nt = 0; nt < 8; ++nt) {
                e[nt] = __expf((p[mt][nt][rr] - mx) * 0.125f);
                l += e[nt];
            }
#pragma unroll
            for (int off = 1; off < 16; off <<= 1) l += __shfl_xor(l, off);
            const float c = Wo[srow] / l;
#pragma unroll
            for (int nt = 0; nt < 8; ++nt) pw[nt] = fmaf(c, e[nt], pw[nt]);
        }
    }
#pragma unroll
    for (int nt = 0; nt < 8; ++nt) {
        pw[nt] += __shfl_xor(pw[nt], 16);
        pw[nt] += __shfl_xor(pw[nt], 32);
    }
    if (q == 0) {
#pragma unroll
        for (int nt = 0; nt < 8; ++nt) sm.wpart[wv][nt * 16 + l15] = pw[nt];
    }
    __syncthreads();
    if (tid < S)
        sm.wfin[tid] = sm.wpart[0][tid] + sm.wpart[1][tid] + sm.wpart[2][tid] + sm.wpart[3][tid];
    __syncthreads();

    {
        const int dd   = tid >> 2;
        const int part = tid & 3;
        const float* xv = xb + (size_t)(h * D + dd) * S + part * 32;
        float a5 = 0.f;
#pragma unroll 8
        for (int t = 0; t < 32; ++t) a5 = fmaf(sm.wfin[part * 32 + t], xv[t], a5);
        a5 += __shfl_xor(a5, 1);
        a5 += __shfl_xor(a5, 2);
        if (part == 0) out[(size_t)b * F + h * D + dd] = a5 + bo[0];
    }
}

extern "C" void kernel_launch(void* const* d_in, const int* in_sizes, int n_in,
                              void* d_out, int out_size, void* d_ws, size_t ws_size,
                              hipStream_t stream) {
    const float* x  = (const float*)d_in[0];
    const float* Wq = (const float*)d_in[1];
    const float* bq = (const float*)d_in[2];
    const float* Wk = (const float*)d_in[3];
    const float* bk = (const float*)d_in[4];
    const float* Wo = (const float*)d_in[5];
    const float* bo = (const float*)d_in[6];
    float* out = (float*)d_out;

    if (ws_size >= WS_NEED) {
        uint4* xs = (uint4*)d_ws;
        uint4* wbp = (uint4*)((char*)d_ws + XS_UNITS * 16);
        prep<<<dim3(4096 + 256), dim3(256), 0, stream>>>(x, Wq, Wk, xs, wbp);
        attn_main<<<dim3(256 * H), dim3(256), 0, stream>>>(x, xs, wbp, bq, bk, Wo, bo, out);
    } else {
        attn_fallback<<<dim3(256 * H), dim3(256), 0, stream>>>(x, Wq, bq, Wk, bk, Wo, bo, out);
    }
}